// Round 4
// baseline (261.452 us; speedup 1.0000x reference)
//
#include <hip/hip_runtime.h>
#include <hip/hip_bf16.h>
#include <math.h>

#define D_MODEL 1024
#define NHEADS  16
#define DK      64
#define SEQ     2048
#define BATCH   2
#define MROWS   4096   // BATCH*SEQ
#define NQT     (SEQ/64)   // 32 q-tiles of 64 rows

typedef unsigned short ushort_t;
using short8 = __attribute__((ext_vector_type(8))) short;
using f32x4  = __attribute__((ext_vector_type(4))) float;

__device__ __forceinline__ ushort_t f2bf(float x) {
    unsigned u = __float_as_uint(x);
    u = (u + 0x7FFFu + ((u >> 16) & 1u)) >> 16;   // RNE
    return (ushort_t)u;
}

// pack 2 floats -> 2 bf16 in one uint (v_cvt_pk_bf16_f32 on gfx950)
__device__ __forceinline__ unsigned pk2(float a, float b) {
    __hip_bfloat162 h = __float22bfloat162_rn(float2{a, b});
    unsigned u;
    __builtin_memcpy(&u, &h, 4);
    return u;
}

// async global->LDS, 16B per lane; LDS dest = wave-uniform base + lane*16
__device__ __forceinline__ void gll16(const ushort_t* g, ushort_t* l) {
    __builtin_amdgcn_global_load_lds(
        (const __attribute__((address_space(1))) void*)(g),
        (__attribute__((address_space(3))) void*)(l), 16, 0, 0);
}

// ---------------------------------------------------------------------------
// fp32 -> bf16 conversion, 7 tensors in one launch (blockIdx.y selects).
// ---------------------------------------------------------------------------
__global__ __launch_bounds__(256) void cvt_bf16(
    const float* s0, const float* s1, const float* s2, const float* s3,
    const float* s4, const float* s5, const float* s6,
    ushort_t* d0, ushort_t* d1, ushort_t* d2, ushort_t* d3,
    ushort_t* d4, ushort_t* d5, ushort_t* d6, int nIn, int nW)
{
    const float* s; ushort_t* d; int n;
    switch (blockIdx.y) {
        case 0: s = s0; d = d0; n = nIn; break;
        case 1: s = s1; d = d1; n = nIn; break;
        case 2: s = s2; d = d2; n = nIn; break;
        case 3: s = s3; d = d3; n = nW;  break;
        case 4: s = s4; d = d4; n = nW;  break;
        case 5: s = s5; d = d5; n = nW;  break;
        default: s = s6; d = d6; n = nW; break;
    }
    int i = (blockIdx.x * 256 + threadIdx.x) * 4;
    if (i < n) {
        float4 v = *(const float4*)&s[i];
        ushort4 o;
        o.x = f2bf(v.x); o.y = f2bf(v.y); o.z = f2bf(v.z); o.w = f2bf(v.w);
        *(ushort4*)&d[i] = o;
    }
}

// ---------------------------------------------------------------------------
// bf16 MFMA GEMM (QKV):  C[M,N] = (A @ W^T + bias) * oscale
// 128x128 tile, BK=64, SINGLE-buffered global_load_lds (r7 structure).
// MODE 0: bf16 row-major out.  MODE 1: bf16 transposed out [B*H][DK][SEQ].
// ---------------------------------------------------------------------------
struct GemmArgs { const ushort_t* A; const ushort_t* W; const float* bias;
                  void* C; int mode; float oscale; };

template<int MODE>
__device__ __forceinline__ void gemm_core(const GemmArgs& ga,
                                          ushort_t* As, ushort_t* Bs)
{
    constexpr bool SWP = (MODE != 1);
    const int tid  = threadIdx.x;
    const int w    = tid >> 6, lane = tid & 63;
    const int quad = lane >> 4, lx = lane & 15;
    const int mw = (w >> 1) * 64, nw = (w & 1) * 64;
    const int bm = blockIdx.x * 128, bn = blockIdx.y * 128;
    const int K = D_MODEL;

    f32x4 acc[4][4];
#pragma unroll
    for (int mt = 0; mt < 4; ++mt)
#pragma unroll
        for (int nt = 0; nt < 4; ++nt)
            acc[mt][nt] = (f32x4){0.f, 0.f, 0.f, 0.f};

    float4 b4[4];
    float  bfr[4];
#pragma unroll
    for (int nt = 0; nt < 4; ++nt) {
        if (SWP) b4[nt] = *(const float4*)&ga.bias[bn + nw + nt * 16 + quad * 4];
        else     bfr[nt] = ga.bias[bn + nw + nt * 16 + lx];
    }

    for (int k0 = 0; k0 < K; k0 += 64) {
        __syncthreads();
#pragma unroll
        for (int i = 0; i < 4; ++i) {
            int r0 = (w * 4 + i) * 8;
            int rl = r0 + (lane >> 3);
            int g  = (lane & 7) ^ (rl & 7);
            gll16(&ga.A[(size_t)(bm + rl) * K + k0 + g * 8], &As[r0 * 64]);
            gll16(&ga.W[(size_t)(bn + rl) * K + k0 + g * 8], &Bs[r0 * 64]);
        }
        __syncthreads();

#pragma unroll
        for (int ks = 0; ks < 2; ++ks) {
            short8 af[4], bf[4];
#pragma unroll
            for (int mt = 0; mt < 4; ++mt) {
                int r = mw + mt * 16 + lx;
                af[mt] = *(const short8*)&As[r * 64 + (((ks * 4 + quad) ^ (r & 7)) << 3)];
            }
#pragma unroll
            for (int nt = 0; nt < 4; ++nt) {
                int r = nw + nt * 16 + lx;
                bf[nt] = *(const short8*)&Bs[r * 64 + (((ks * 4 + quad) ^ (r & 7)) << 3)];
            }
#pragma unroll
            for (int mt = 0; mt < 4; ++mt)
#pragma unroll
                for (int nt = 0; nt < 4; ++nt)
                    acc[mt][nt] = SWP
                        ? __builtin_amdgcn_mfma_f32_16x16x32_bf16(bf[nt], af[mt], acc[mt][nt], 0, 0, 0)
                        : __builtin_amdgcn_mfma_f32_16x16x32_bf16(af[mt], bf[nt], acc[mt][nt], 0, 0, 0);
        }
    }

    if (MODE == 0) {
        ushort_t* C = (ushort_t*)ga.C;
        const float os = ga.oscale;
#pragma unroll
        for (int mt = 0; mt < 4; ++mt) {
            int m = bm + mw + mt * 16 + lx;
#pragma unroll
            for (int nt = 0; nt < 4; ++nt) {
                int n0 = bn + nw + nt * 16 + quad * 4;
                uint2 u;
                u.x = pk2((acc[mt][nt][0] + b4[nt].x) * os, (acc[mt][nt][1] + b4[nt].y) * os);
                u.y = pk2((acc[mt][nt][2] + b4[nt].z) * os, (acc[mt][nt][3] + b4[nt].w) * os);
                *(uint2*)&C[(size_t)m * D_MODEL + n0] = u;
            }
        }
    } else {
        ushort_t* C = (ushort_t*)ga.C;
#pragma unroll
        for (int mt = 0; mt < 4; ++mt)
#pragma unroll
            for (int nt = 0; nt < 4; ++nt) {
                int n = bn + nw + nt * 16 + lx;
                int d = n & 63, h = n >> 6;
                int m0 = bm + mw + mt * 16 + quad * 4;
                int b = m0 >> 11, s0 = m0 & 2047;
                uint2 u;
                u.x = pk2(acc[mt][nt][0] + bfr[nt], acc[mt][nt][1] + bfr[nt]);
                u.y = pk2(acc[mt][nt][2] + bfr[nt], acc[mt][nt][3] + bfr[nt]);
                *(uint2*)&C[((size_t)(b * NHEADS + h) * DK + d) * SEQ + s0] = u;
            }
    }
}

__global__ __launch_bounds__(256) void gemm_mfma(GemmArgs g0, GemmArgs g1, GemmArgs g2)
{
    __shared__ ushort_t As[128 * 64];
    __shared__ ushort_t Bs[128 * 64];
    GemmArgs ga = (blockIdx.z == 0) ? g0 : ((blockIdx.z == 1) ? g1 : g2);
    if (ga.mode == 0) gemm_core<0>(ga, As, Bs);
    else              gemm_core<1>(ga, As, Bs);
}

// ---------------------------------------------------------------------------
// O-projection GEMM: out[M,N] = Hc @ Wo^T + bo, fp32 out.
// ---------------------------------------------------------------------------
__global__ __launch_bounds__(256) void gemm_o(
    const ushort_t* __restrict__ A, const ushort_t* __restrict__ W,
    const float* __restrict__ bias, float* __restrict__ C)
{
    __shared__ ushort_t As[64 * 64];
    __shared__ ushort_t Bs[128 * 64];

    const int tid  = threadIdx.x;
    const int w    = tid >> 6, lane = tid & 63;
    const int quad = lane >> 4, lx = lane & 15;
    const int mw = (w >> 1) * 32, nw = (w & 1) * 64;
    const int bm = blockIdx.x * 64, bn = blockIdx.y * 128;
    const int K = D_MODEL;

    f32x4 acc[2][4];
#pragma unroll
    for (int mt = 0; mt < 2; ++mt)
#pragma unroll
        for (int nt = 0; nt < 4; ++nt)
            acc[mt][nt] = (f32x4){0.f, 0.f, 0.f, 0.f};

    float4 b4[4];
#pragma unroll
    for (int nt = 0; nt < 4; ++nt)
        b4[nt] = *(const float4*)&bias[bn + nw + nt * 16 + quad * 4];

    for (int k0 = 0; k0 < K; k0 += 64) {
        __syncthreads();
#pragma unroll
        for (int i = 0; i < 2; ++i) {
            int r0 = (i * 4 + w) * 8;
            int rl = r0 + (lane >> 3);
            int g  = (lane & 7) ^ (rl & 7);
            gll16(&A[(size_t)(bm + rl) * K + k0 + g * 8], &As[r0 * 64]);
        }
#pragma unroll
        for (int i = 0; i < 4; ++i) {
            int r0 = (i * 4 + w) * 8;
            int rl = r0 + (lane >> 3);
            int g  = (lane & 7) ^ (rl & 7);
            gll16(&W[(size_t)(bn + rl) * K + k0 + g * 8], &Bs[r0 * 64]);
        }
        __syncthreads();

#pragma unroll
        for (int ks = 0; ks < 2; ++ks) {
            short8 af[2], bf[4];
#pragma unroll
            for (int mt = 0; mt < 2; ++mt) {
                int r = mw + mt * 16 + lx;
                af[mt] = *(const short8*)&As[r * 64 + (((ks * 4 + quad) ^ (r & 7)) << 3)];
            }
#pragma unroll
            for (int nt = 0; nt < 4; ++nt) {
                int r = nw + nt * 16 + lx;
                bf[nt] = *(const short8*)&Bs[r * 64 + (((ks * 4 + quad) ^ (r & 7)) << 3)];
            }
#pragma unroll
            for (int mt = 0; mt < 2; ++mt)
#pragma unroll
                for (int nt = 0; nt < 4; ++nt)
                    acc[mt][nt] = __builtin_amdgcn_mfma_f32_16x16x32_bf16(
                        bf[nt], af[mt], acc[mt][nt], 0, 0, 0);
        }
    }

#pragma unroll
    for (int mt = 0; mt < 2; ++mt) {
        int m = bm + mw + mt * 16 + lx;
#pragma unroll
        for (int nt = 0; nt < 4; ++nt) {
            int n0 = bn + nw + nt * 16 + quad * 4;
            float4 v;
            v.x = acc[mt][nt][0] + b4[nt].x;
            v.y = acc[mt][nt][1] + b4[nt].y;
            v.z = acc[mt][nt][2] + b4[nt].z;
            v.w = acc[mt][nt][3] + b4[nt].w;
            *(float4*)&C[(size_t)m * D_MODEL + n0] = v;
        }
    }
}

// ---------------------------------------------------------------------------
// bf16 MFMA causal flash attention — r12: WAVE-AUTONOMOUS, ZERO BARRIERS.
// Post-mortem r7/r9/r10/r11: all structures land at 50-55µs regardless of
// occupancy (12-23%), DS traffic (2x range), VALU mix — the limiter is the
// barrier-lockstep serial chain: 4 barrier-synced waves march in phase
// through ds_read burst -> MFMA -> ~550cyc softmax -> P round-trip, each
// pipe hit in bursts then idle. r12: one wave (64 thr) per block owns a
// 64-row q-tile: Q(4 groups)+O in registers, PRIVATE single-buffered K/V
// (16KB) + P scratch (2KB) in LDS. Loop: vmcnt(0) -> 16 ds_read K/V frags
// to regs -> lgkmcnt(0) -> stage kt+1 into same buffer (16 gll16) -> 4
// independent per-group chains {QK 8-MFMA -> softmax -> P LDS round-trip
// -> PV 8-MFMA} = 4-way ILP for the scheduler. No s_barrier anywhere.
// K/V frag reads feed 4 q-groups: MFMA:DS = 64:20 per iter.
// ---------------------------------------------------------------------------
__global__ __launch_bounds__(64) void flash_mfma(
    const ushort_t* __restrict__ Qp, const ushort_t* __restrict__ Kp,
    const ushort_t* __restrict__ Vt, ushort_t* __restrict__ Hc)
{
    __shared__ ushort_t Ks[64 * 64];                 // 8KB, single-buffered
    __shared__ ushort_t Vs[64 * 64];                 // 8KB, single-buffered
    __shared__ __align__(16) ushort_t Ps[16 * 64];   // 2KB P scratch

    // r9's proven swizzle: XCD c gets heads {c,c+8,c+16,c+24}; per-CU
    // quartet qt = {u, 31-u, (u+8)&31, 31-((u+8)&31)} -> 66 iters balanced.
    const int flat = blockIdx.x;          // 0..1023
    const int c  = flat & 7;              // XCD
    const int j  = flat >> 3;             // 0..127 within XCD
    const int cu = j & 31;
    const int m  = j >> 5;                // 0..3
    const int bh = c + (m << 3);
    const int u  = (cu + ((m >> 1) << 3)) & 31;
    const int qt = (m & 1) ? (NQT - 1 - u) : u;
    const int b = bh >> 4, h = bh & 15;

    const size_t qbase = (size_t)(b * SEQ) * D_MODEL + h * DK;
    const size_t vbase = (size_t)bh * DK * SEQ;

    const int lane = threadIdx.x;         // 0..63
    const int quad = lane >> 4, lx = lane & 15;

    // prologue: stage K(0), V(0)
#pragma unroll
    for (int i = 0; i < 8; ++i) {
        int r0 = i * 8;
        int rl = r0 + (lane >> 3);
        int g  = (lane & 7) ^ (rl & 7);
        gll16(&Kp[qbase + (size_t)rl * D_MODEL + g * 8], &Ks[r0 * 64]);
        gll16(&Vt[vbase + (size_t)rl * SEQ + g * 8], &Vs[r0 * 64]);
    }

    // Q fragments, 4 groups of 16 rows (rows qt*64 + g*16 + lx)
    short8 qf[4][2];
#pragma unroll
    for (int g = 0; g < 4; ++g) {
        size_t ro = qbase + (size_t)(qt * 64 + g * 16 + lx) * D_MODEL + quad * 8;
        qf[g][0] = *(const short8*)&Qp[ro];
        qf[g][1] = *(const short8*)&Qp[ro + 32];
    }

    // per-lane P row base: pad-free 128B rows, XOR-16B swizzle on (lx&7)
    char* Pb = (char*)&Ps[0] + (lx << 7);
    const int hsw = (lx & 7) << 4;

    f32x4 O[4][4];        // [g][nt]: d = nt*16+quad*4+r, q = lx
#pragma unroll
    for (int g = 0; g < 4; ++g)
#pragma unroll
        for (int nt = 0; nt < 4; ++nt)
            O[g][nt] = (f32x4){0.f, 0.f, 0.f, 0.f};
    float mg[4] = {-INFINITY, -INFINITY, -INFINITY, -INFINITY};
    float lg[4] = {0.f, 0.f, 0.f, 0.f};

    for (int kt = 0; kt <= qt; ++kt) {
        // tile-kt staging (issued last iter / prologue) must have landed
        asm volatile("s_waitcnt vmcnt(0)" ::: "memory");

        // pull ALL K and V fragments into registers
        short8 kf[4][2], vf[4][2];
#pragma unroll
        for (int nt = 0; nt < 4; ++nt) {
            int r = nt * 16 + lx;
            kf[nt][0] = *(const short8*)&Ks[r * 64 + ((quad ^ (r & 7)) << 3)];
            kf[nt][1] = *(const short8*)&Ks[r * 64 + (((4 + quad) ^ (r & 7)) << 3)];
            vf[nt][0] = *(const short8*)&Vs[r * 64 + ((quad ^ (r & 7)) << 3)];
            vf[nt][1] = *(const short8*)&Vs[r * 64 + (((4 + quad) ^ (r & 7)) << 3)];
        }
        // frags must be in regs before the same buffers are overwritten
        asm volatile("s_waitcnt lgkmcnt(0)" ::: "memory");
        __builtin_amdgcn_sched_barrier(0);

        // stage tile kt+1 into the SAME buffers (no other wave touches them)
        if (kt < qt) {
#pragma unroll
            for (int i = 0; i < 8; ++i) {
                int r0 = i * 8;
                int rl = r0 + (lane >> 3);
                int g2 = (lane & 7) ^ (rl & 7);
                gll16(&Kp[qbase + (size_t)((kt + 1) * 64 + rl) * D_MODEL + g2 * 8], &Ks[r0 * 64]);
                gll16(&Vt[vbase + (size_t)rl * SEQ + (kt + 1) * 64 + g2 * 8], &Vs[r0 * 64]);
            }
        }

        const bool diag = (kt == qt);

        // 4 independent per-group chains: QK -> softmax -> P -> PV.
        // Group g+1's QK (MFMA pipe) overlaps group g's softmax (VALU pipe).
#pragma unroll
        for (int g = 0; g < 4; ++g) {
            // S^T = K Q^T : s[nt][r] = S[q=lx][k = nt*16+quad*4+r]
            f32x4 s[4];
            __builtin_amdgcn_s_setprio(1);
#pragma unroll
            for (int nt = 0; nt < 4; ++nt) {
                f32x4 z = (f32x4){0.f, 0.f, 0.f, 0.f};
                z = __builtin_amdgcn_mfma_f32_16x16x32_bf16(kf[nt][0], qf[g][0], z, 0, 0, 0);
                z = __builtin_amdgcn_mfma_f32_16x16x32_bf16(kf[nt][1], qf[g][1], z, 0, 0, 0);
                s[nt] = z;
            }
            __builtin_amdgcn_s_setprio(0);

            if (diag) {
                const int qd = g * 16 + lx;
#pragma unroll
                for (int nt = 0; nt < 4; ++nt)
#pragma unroll
                    for (int r = 0; r < 4; ++r)
                        if ((nt * 16 + quad * 4 + r) > qd) s[nt][r] = -INFINITY;
            }

            // online softmax (tree max/sum; defer-max THR=8 in log2 domain)
            float a0 = fmaxf(fmaxf(s[0][0], s[0][1]), fmaxf(s[0][2], s[0][3]));
            float a1 = fmaxf(fmaxf(s[1][0], s[1][1]), fmaxf(s[1][2], s[1][3]));
            float a2 = fmaxf(fmaxf(s[2][0], s[2][1]), fmaxf(s[2][2], s[2][3]));
            float a3 = fmaxf(fmaxf(s[3][0], s[3][1]), fmaxf(s[3][2], s[3][3]));
            float tm = fmaxf(fmaxf(a0, a1), fmaxf(a2, a3));
            tm = fmaxf(tm, __shfl_xor(tm, 16, 64));
            tm = fmaxf(tm, __shfl_xor(tm, 32, 64));
            if (__any(tm > mg[g] + 8.f)) {
                float mnew = fmaxf(mg[g], tm);
                float alpha = __builtin_amdgcn_exp2f(mg[g] - mnew);
                mg[g] = mnew;
                lg[g] *= alpha;
#pragma unroll
                for (int nt = 0; nt < 4; ++nt)
#pragma unroll
                    for (int r = 0; r < 4; ++r) O[g][nt][r] *= alpha;
            }
#pragma unroll
            for (int nt = 0; nt < 4; ++nt)
#pragma unroll
                for (int r = 0; r < 4; ++r)
                    s[nt][r] = __builtin_amdgcn_exp2f(s[nt][r] - mg[g]);
            float r0s = (s[0][0] + s[0][1]) + (s[0][2] + s[0][3]);
            float r1s = (s[1][0] + s[1][1]) + (s[1][2] + s[1][3]);
            float r2s = (s[2][0] + s[2][1]) + (s[2][2] + s[2][3]);
            float r3s = (s[3][0] + s[3][1]) + (s[3][2] + s[3][3]);
            float rs = (r0s + r1s) + (r2s + r3s);
            rs += __shfl_xor(rs, 16, 64);
            rs += __shfl_xor(rs, 32, 64);
            lg[g] += rs;

            // P round-trip through wave-private LDS (in-order DS per wave)
#pragma unroll
            for (int nt = 0; nt < 4; ++nt) {
                uint2 pu;
                pu.x = pk2(s[nt][0], s[nt][1]);
                pu.y = pk2(s[nt][2], s[nt][3]);
                *(uint2*)(Pb + ((nt * 32 + quad * 8) ^ hsw)) = pu;
            }
            short8 pf0 = *(const short8*)(Pb + ((quad * 16) ^ hsw));
            short8 pf1 = *(const short8*)(Pb + ((64 + quad * 16) ^ hsw));

            // O^T += V^T-frag x P-frag
            __builtin_amdgcn_s_setprio(1);
#pragma unroll
            for (int nt = 0; nt < 4; ++nt) {
                O[g][nt] = __builtin_amdgcn_mfma_f32_16x16x32_bf16(vf[nt][0], pf0, O[g][nt], 0, 0, 0);
                O[g][nt] = __builtin_amdgcn_mfma_f32_16x16x32_bf16(vf[nt][1], pf1, O[g][nt], 0, 0, 0);
            }
            __builtin_amdgcn_s_setprio(0);
        }
    }

    // epilogue: lane writes row q = g*16+lx, 4 consecutive d per nt
#pragma unroll
    for (int g = 0; g < 4; ++g) {
        float invl = 1.f / lg[g];
        size_t ro = qbase + (size_t)(qt * 64 + g * 16 + lx) * D_MODEL;
#pragma unroll
        for (int nt = 0; nt < 4; ++nt) {
            uint2 pu;
            pu.x = pk2(O[g][nt][0] * invl, O[g][nt][1] * invl);
            pu.y = pk2(O[g][nt][2] * invl, O[g][nt][3] * invl);
            *(uint2*)&Hc[ro + nt * 16 + quad * 4] = pu;
        }
    }
}

extern "C" void kernel_launch(void* const* d_in, const int* in_sizes, int n_in,
                              void* d_out, int out_size, void* d_ws, size_t ws_size,
                              hipStream_t stream) {
    const float* inQ = (const float*)d_in[0];
    const float* inK = (const float*)d_in[1];
    const float* inV = (const float*)d_in[2];
    const float* Wq  = (const float*)d_in[3];
    const float* bq  = (const float*)d_in[4];
    const float* Wk  = (const float*)d_in[5];
    const float* bk  = (const float*)d_in[6];
    const float* Wv  = (const float*)d_in[7];
    const float* bv  = (const float*)d_in[8];
    const float* Wo  = (const float*)d_in[9];
    const float* bo  = (const float*)d_in[10];
    float* out = (float*)d_out;

    const size_t NI = (size_t)MROWS * D_MODEL;      // 4M
    const size_t NW = (size_t)D_MODEL * D_MODEL;    // 1M
    ushort_t* ws  = (ushort_t*)d_ws;
    ushort_t* Qb  = ws;                // bf16 inputs
    ushort_t* Kb  = Qb  + NI;
    ushort_t* Vb  = Kb  + NI;
    ushort_t* Wqb = Vb  + NI;          // bf16 weights
    ushort_t* Wkb = Wqb + NW;
    ushort_t* Wvb = Wkb + NW;
    ushort_t* Wob = Wvb + NW;
    ushort_t* Qp  = Wob + NW;          // projections
    ushort_t* Kp  = Qp  + NI;
    ushort_t* Vtg = Kp  + NI;          // V^T [B*H][DK][SEQ]
    ushort_t* Hc  = Vtg + NI;

    // fp32 -> bf16 (all 7 tensors, one launch)
    cvt_bf16<<<dim3(NI / 1024, 7), 256, 0, stream>>>(
        inQ, inK, inV, Wq, Wk, Wv, Wo,
        Qb, Kb, Vb, Wqb, Wkb, Wvb, Wob, (int)NI, (int)NW);

    // fused QKV projection; Q pre-scaled by 1/sqrt(dk)*log2(e); V transposed
    const float qsc = 0.125f * 1.44269504088896340736f;
    GemmArgs aq{Qb, Wqb, bq, (void*)Qp, 0, qsc};
    GemmArgs ak{Kb, Wkb, bk, (void*)Kp, 0, 1.0f};
    GemmArgs av{Vb, Wvb, bv, (void*)Vtg, 1, 1.0f};
    gemm_mfma<<<dim3(MROWS / 128, D_MODEL / 128, 3), 256, 0, stream>>>(aq, ak, av);

    // attention: wave-autonomous, 1024 one-wave blocks, zero barriers
    flash_mfma<<<dim3(NQT * BATCH * NHEADS), 64, 0, stream>>>(Qp, Kp, Vtg, Hc);

    // output projection (fp32 out), 64x128 single-buffer tiles, 512 blocks
    gemm_o<<<dim3(MROWS / 64, D_MODEL / 128), 256, 0, stream>>>(Hc, Wob, bo, out);
}

// Round 5
// 212.868 us; speedup vs baseline: 1.2282x; 1.2282x over previous
//
#include <hip/hip_runtime.h>
#include <hip/hip_bf16.h>
#include <math.h>

#define D_MODEL 1024
#define NHEADS  16
#define DK      64
#define SEQ     2048
#define BATCH   2
#define MROWS   4096   // BATCH*SEQ
#define NQT     (SEQ/64)   // 32 q-tiles

typedef unsigned short ushort_t;
using short8 = __attribute__((ext_vector_type(8))) short;
using f32x4  = __attribute__((ext_vector_type(4))) float;

__device__ __forceinline__ ushort_t f2bf(float x) {
    unsigned u = __float_as_uint(x);
    u = (u + 0x7FFFu + ((u >> 16) & 1u)) >> 16;   // RNE
    return (ushort_t)u;
}

// pack 2 floats -> 2 bf16 in one uint (v_cvt_pk_bf16_f32 on gfx950)
__device__ __forceinline__ unsigned pk2(float a, float b) {
    __hip_bfloat162 h = __float22bfloat162_rn(float2{a, b});
    unsigned u;
    __builtin_memcpy(&u, &h, 4);
    return u;
}

// async global->LDS, 16B per lane; LDS dest = wave-uniform base + lane*16
__device__ __forceinline__ void gll16(const ushort_t* g, ushort_t* l) {
    __builtin_amdgcn_global_load_lds(
        (const __attribute__((address_space(1))) void*)(g),
        (__attribute__((address_space(3))) void*)(l), 16, 0, 0);
}

// ---------------------------------------------------------------------------
// fp32 -> bf16 conversion, 7 tensors in one launch (blockIdx.y selects).
// ---------------------------------------------------------------------------
__global__ __launch_bounds__(256) void cvt_bf16(
    const float* s0, const float* s1, const float* s2, const float* s3,
    const float* s4, const float* s5, const float* s6,
    ushort_t* d0, ushort_t* d1, ushort_t* d2, ushort_t* d3,
    ushort_t* d4, ushort_t* d5, ushort_t* d6, int nIn, int nW)
{
    const float* s; ushort_t* d; int n;
    switch (blockIdx.y) {
        case 0: s = s0; d = d0; n = nIn; break;
        case 1: s = s1; d = d1; n = nIn; break;
        case 2: s = s2; d = d2; n = nIn; break;
        case 3: s = s3; d = d3; n = nW;  break;
        case 4: s = s4; d = d4; n = nW;  break;
        case 5: s = s5; d = d5; n = nW;  break;
        default: s = s6; d = d6; n = nW; break;
    }
    int i = (blockIdx.x * 256 + threadIdx.x) * 4;
    if (i < n) {
        float4 v = *(const float4*)&s[i];
        ushort4 o;
        o.x = f2bf(v.x); o.y = f2bf(v.y); o.z = f2bf(v.z); o.w = f2bf(v.w);
        *(ushort4*)&d[i] = o;
    }
}

// ---------------------------------------------------------------------------
// bf16 MFMA GEMM (QKV):  128x128 tile, BK=64, single-buffered gll16.
// MODE 0: C[M,N] = (A @ W^T + bias)*oscale, bf16 row-major out.
// MODE 1 (V^T): computed as the TRANSPOSED gemm — A'=Wv (M'=1024 channels),
//   B'=Vb (N'=4096 rows) — so the standard epilogue emits rows of
//   V^T[bh][d][s] with 4 consecutive s per uint2: fully coalesced stores
//   (the old direct form scattered 8B stores at 4KB stride).
// ---------------------------------------------------------------------------
struct GemmArgs { const ushort_t* A; const ushort_t* W; const float* bias;
                  void* C; int mode; float oscale; };

template<int MODE>
__device__ __forceinline__ void gemm_core(const GemmArgs& ga,
                                          ushort_t* As, ushort_t* Bs)
{
    const int tid  = threadIdx.x;
    const int w    = tid >> 6, lane = tid & 63;
    const int quad = lane >> 4, lx = lane & 15;
    const int mw = (w >> 1) * 64, nw = (w & 1) * 64;
    // MODE1 swaps the roles of the grid dims: M'=1024 (8 tiles via y),
    // N'=4096 (32 tiles via x).
    const int bm = (MODE == 1 ? blockIdx.y : blockIdx.x) * 128;
    const int bn = (MODE == 1 ? blockIdx.x : blockIdx.y) * 128;
    const int K = D_MODEL;

    f32x4 acc[4][4];
#pragma unroll
    for (int mt = 0; mt < 4; ++mt)
#pragma unroll
        for (int nt = 0; nt < 4; ++nt)
            acc[mt][nt] = (f32x4){0.f, 0.f, 0.f, 0.f};

    float4 b4[4];
    float  bfr[4];
#pragma unroll
    for (int i = 0; i < 4; ++i) {
        if (MODE == 0) b4[i]  = *(const float4*)&ga.bias[bn + nw + i * 16 + quad * 4];
        else           bfr[i] = ga.bias[bm + mw + i * 16 + lx];   // per-row bias
    }

    for (int k0 = 0; k0 < K; k0 += 64) {
        __syncthreads();
#pragma unroll
        for (int i = 0; i < 4; ++i) {
            int r0 = (w * 4 + i) * 8;
            int rl = r0 + (lane >> 3);
            int g  = (lane & 7) ^ (rl & 7);
            gll16(&ga.A[(size_t)(bm + rl) * K + k0 + g * 8], &As[r0 * 64]);
            gll16(&ga.W[(size_t)(bn + rl) * K + k0 + g * 8], &Bs[r0 * 64]);
        }
        __syncthreads();

#pragma unroll
        for (int ks = 0; ks < 2; ++ks) {
            short8 af[4], bf[4];
#pragma unroll
            for (int mt = 0; mt < 4; ++mt) {
                int r = mw + mt * 16 + lx;
                af[mt] = *(const short8*)&As[r * 64 + (((ks * 4 + quad) ^ (r & 7)) << 3)];
            }
#pragma unroll
            for (int nt = 0; nt < 4; ++nt) {
                int r = nw + nt * 16 + lx;
                bf[nt] = *(const short8*)&Bs[r * 64 + (((ks * 4 + quad) ^ (r & 7)) << 3)];
            }
#pragma unroll
            for (int mt = 0; mt < 4; ++mt)
#pragma unroll
                for (int nt = 0; nt < 4; ++nt)
                    acc[mt][nt] = __builtin_amdgcn_mfma_f32_16x16x32_bf16(
                        bf[nt], af[mt], acc[mt][nt], 0, 0, 0);
        }
    }

    // epilogue: lane holds m = ..+lx (row), 4 consecutive n per nt.
    if (MODE == 0) {
        ushort_t* C = (ushort_t*)ga.C;
        const float os = ga.oscale;
#pragma unroll
        for (int mt = 0; mt < 4; ++mt) {
            int m = bm + mw + mt * 16 + lx;
#pragma unroll
            for (int nt = 0; nt < 4; ++nt) {
                int n0 = bn + nw + nt * 16 + quad * 4;
                uint2 u;
                u.x = pk2((acc[mt][nt][0] + b4[nt].x) * os, (acc[mt][nt][1] + b4[nt].y) * os);
                u.y = pk2((acc[mt][nt][2] + b4[nt].z) * os, (acc[mt][nt][3] + b4[nt].w) * os);
                *(uint2*)&C[(size_t)m * D_MODEL + n0] = u;
            }
        }
    } else {
        // row = channel ch (h = ch>>6, d = ch&63); col = token n0 (b, s)
        ushort_t* C = (ushort_t*)ga.C;
#pragma unroll
        for (int mt = 0; mt < 4; ++mt) {
            int ch = bm + mw + mt * 16 + lx;
            int h = ch >> 6, d = ch & 63;
            float bb = bfr[mt];
#pragma unroll
            for (int nt = 0; nt < 4; ++nt) {
                int n0 = bn + nw + nt * 16 + quad * 4;
                int b = n0 >> 11, s0 = n0 & 2047;
                uint2 u;
                u.x = pk2(acc[mt][nt][0] + bb, acc[mt][nt][1] + bb);
                u.y = pk2(acc[mt][nt][2] + bb, acc[mt][nt][3] + bb);
                *(uint2*)&C[((size_t)(b * NHEADS + h) * DK + d) * SEQ + s0] = u;
            }
        }
    }
}

__global__ __launch_bounds__(256) void gemm_mfma(GemmArgs g0, GemmArgs g1, GemmArgs g2)
{
    __shared__ ushort_t As[128 * 64];
    __shared__ ushort_t Bs[128 * 64];
    GemmArgs ga = (blockIdx.z == 0) ? g0 : ((blockIdx.z == 1) ? g1 : g2);
    if (ga.mode == 0) gemm_core<0>(ga, As, Bs);
    else              gemm_core<1>(ga, As, Bs);
}

// ---------------------------------------------------------------------------
// O-projection GEMM: out[M,N] = Hc @ Wo^T + bo, fp32 out.
// ---------------------------------------------------------------------------
__global__ __launch_bounds__(256) void gemm_o(
    const ushort_t* __restrict__ A, const ushort_t* __restrict__ W,
    const float* __restrict__ bias, float* __restrict__ C)
{
    __shared__ ushort_t As[64 * 64];
    __shared__ ushort_t Bs[128 * 64];

    const int tid  = threadIdx.x;
    const int w    = tid >> 6, lane = tid & 63;
    const int quad = lane >> 4, lx = lane & 15;
    const int mw = (w >> 1) * 32, nw = (w & 1) * 64;
    const int bm = blockIdx.x * 64, bn = blockIdx.y * 128;
    const int K = D_MODEL;

    f32x4 acc[2][4];
#pragma unroll
    for (int mt = 0; mt < 2; ++mt)
#pragma unroll
        for (int nt = 0; nt < 4; ++nt)
            acc[mt][nt] = (f32x4){0.f, 0.f, 0.f, 0.f};

    float4 b4[4];
#pragma unroll
    for (int nt = 0; nt < 4; ++nt)
        b4[nt] = *(const float4*)&bias[bn + nw + nt * 16 + quad * 4];

    for (int k0 = 0; k0 < K; k0 += 64) {
        __syncthreads();
#pragma unroll
        for (int i = 0; i < 2; ++i) {
            int r0 = (i * 4 + w) * 8;
            int rl = r0 + (lane >> 3);
            int g  = (lane & 7) ^ (rl & 7);
            gll16(&A[(size_t)(bm + rl) * K + k0 + g * 8], &As[r0 * 64]);
        }
#pragma unroll
        for (int i = 0; i < 4; ++i) {
            int r0 = (i * 4 + w) * 8;
            int rl = r0 + (lane >> 3);
            int g  = (lane & 7) ^ (rl & 7);
            gll16(&W[(size_t)(bn + rl) * K + k0 + g * 8], &Bs[r0 * 64]);
        }
        __syncthreads();

#pragma unroll
        for (int ks = 0; ks < 2; ++ks) {
            short8 af[2], bf[4];
#pragma unroll
            for (int mt = 0; mt < 2; ++mt) {
                int r = mw + mt * 16 + lx;
                af[mt] = *(const short8*)&As[r * 64 + (((ks * 4 + quad) ^ (r & 7)) << 3)];
            }
#pragma unroll
            for (int nt = 0; nt < 4; ++nt) {
                int r = nw + nt * 16 + lx;
                bf[nt] = *(const short8*)&Bs[r * 64 + (((ks * 4 + quad) ^ (r & 7)) << 3)];
            }
#pragma unroll
            for (int mt = 0; mt < 2; ++mt)
#pragma unroll
                for (int nt = 0; nt < 4; ++nt)
                    acc[mt][nt] = __builtin_amdgcn_mfma_f32_16x16x32_bf16(
                        bf[nt], af[mt], acc[mt][nt], 0, 0, 0);
        }
    }

#pragma unroll
    for (int mt = 0; mt < 2; ++mt) {
        int m = bm + mw + mt * 16 + lx;
#pragma unroll
        for (int nt = 0; nt < 4; ++nt) {
            int n0 = bn + nw + nt * 16 + quad * 4;
            float4 v;
            v.x = acc[mt][nt][0] + b4[nt].x;
            v.y = acc[mt][nt][1] + b4[nt].y;
            v.z = acc[mt][nt][2] + b4[nt].z;
            v.w = acc[mt][nt][3] + b4[nt].w;
            *(float4*)&C[(size_t)m * D_MODEL + n0] = v;
        }
    }
}

// ---------------------------------------------------------------------------
// bf16 MFMA causal flash attention — r13 = r9 (best measured: 50.6µs)
// with two algebraically-safe softmax latency cuts:
//  (1) defer-max gate on the PER-LANE max (single __any ballot); the 2-shfl
//      max-reduce runs only when the gate fires (rare in steady state).
//  (2) l kept as a per-lane partial; its 2-shfl cross-lane reduce moved to
//      the epilogue (alpha is row-uniform so partials scale identically).
// Steady-state iteration now has ZERO shfl ops in the serial chain.
// ---------------------------------------------------------------------------
__device__ __forceinline__ void flash_tile(
    int qt, const size_t qbase, const size_t vbase,
    const ushort_t* __restrict__ Qp, const ushort_t* __restrict__ Kp,
    const ushort_t* __restrict__ Vt, ushort_t* __restrict__ Hc,
    ushort_t* Ks0, ushort_t* Ks1, ushort_t* Vs0, ushort_t* Vs1,
    ushort_t (*Ps)[16 * 64])
{
    const int tid  = threadIdx.x;
    const int w    = tid >> 6, lane = tid & 63;
    const int quad = lane >> 4, lx = lane & 15;

    // prologue: stage k-tile 0 into buffer 0
    {
#pragma unroll
        for (int i = 0; i < 2; ++i) {
            int r0 = (w + i * 4) * 8;
            int rl = r0 + (lane >> 3);
            int g  = (lane & 7) ^ (rl & 7);
            gll16(&Kp[qbase + (size_t)rl * D_MODEL + g * 8], &Ks0[r0 * 64]);
            gll16(&Vt[vbase + (size_t)rl * SEQ + g * 8], &Vs0[r0 * 64]);
        }
    }

    // Q fragments (row qt*64 + w*16 + lx), resident across all k-tiles
    short8 qf[2];
    {
        size_t ro = qbase + (size_t)(qt * 64 + w * 16 + lx) * D_MODEL + quad * 8;
        qf[0] = *(const short8*)&Qp[ro];
        qf[1] = *(const short8*)&Qp[ro + 32];
    }

    // per-wave P row base: pad-free 128B rows, XOR-16B swizzle on (lx&7)
    char* Pb = (char*)&Ps[w][0] + (lx << 7);
    const int hsw = (lx & 7) << 4;

    f32x4 O[4];           // O^T frags: d = nt*16+quad*4+r, q = lx
#pragma unroll
    for (int nt = 0; nt < 4; ++nt) O[nt] = (f32x4){0.f, 0.f, 0.f, 0.f};
    float mrow = -INFINITY, lrow = 0.f;   // mrow row-uniform; lrow PER-LANE partial
    const int qin = w * 16 + lx;          // q index within the 64-row tile

    for (int kt = 0; kt <= qt; ++kt) {
        ushort_t* Ks = (kt & 1) ? Ks1 : Ks0;
        ushort_t* Vs = (kt & 1) ? Vs1 : Vs0;

        // tile-kt loads were issued one full iteration ago
        asm volatile("s_waitcnt vmcnt(0)" ::: "memory");
        asm volatile("s_barrier" ::: "memory");

        // prefetch k-tile kt+1 into the other buffer (overlaps compute below)
        if (kt < qt) {
            ushort_t* Kn = (kt & 1) ? Ks0 : Ks1;
            ushort_t* Vn = (kt & 1) ? Vs0 : Vs1;
#pragma unroll
            for (int i = 0; i < 2; ++i) {
                int r0 = (w + i * 4) * 8;
                int rl = r0 + (lane >> 3);
                int g  = (lane & 7) ^ (rl & 7);
                gll16(&Kp[qbase + (size_t)((kt + 1) * 64 + rl) * D_MODEL + g * 8], &Kn[r0 * 64]);
                gll16(&Vt[vbase + (size_t)rl * SEQ + (kt + 1) * 64 + g * 8], &Vn[r0 * 64]);
            }
        }

        // S^T = K Q^T : s[nt][r] = S[q=lx][k = nt*16+quad*4+r]
        f32x4 s[4];
        __builtin_amdgcn_s_setprio(1);
#pragma unroll
        for (int nt = 0; nt < 4; ++nt) {
            int r = nt * 16 + lx;
            short8 kf0 = *(const short8*)&Ks[r * 64 + ((quad ^ (r & 7)) << 3)];
            short8 kf1 = *(const short8*)&Ks[r * 64 + (((4 + quad) ^ (r & 7)) << 3)];
            f32x4 z = (f32x4){0.f, 0.f, 0.f, 0.f};
            z = __builtin_amdgcn_mfma_f32_16x16x32_bf16(kf0, qf[0], z, 0, 0, 0);
            z = __builtin_amdgcn_mfma_f32_16x16x32_bf16(kf1, qf[1], z, 0, 0, 0);
            s[nt] = z;
        }
        __builtin_amdgcn_s_setprio(0);

        // causal mask (diagonal tile only); values already in log2 domain
        if (kt == qt) {
#pragma unroll
            for (int nt = 0; nt < 4; ++nt)
#pragma unroll
                for (int r = 0; r < 4; ++r)
                    if ((nt * 16 + quad * 4 + r) > qin) s[nt][r] = -INFINITY;
        }

        // per-lane max (tree); cross-lane reduce only if the gate fires
        float a0 = fmaxf(fmaxf(s[0][0], s[0][1]), fmaxf(s[0][2], s[0][3]));
        float a1 = fmaxf(fmaxf(s[1][0], s[1][1]), fmaxf(s[1][2], s[1][3]));
        float a2 = fmaxf(fmaxf(s[2][0], s[2][1]), fmaxf(s[2][2], s[2][3]));
        float a3 = fmaxf(fmaxf(s[3][0], s[3][1]), fmaxf(s[3][2], s[3][3]));
        float lm = fmaxf(fmaxf(a0, a1), fmaxf(a2, a3));
        if (__any(lm > mrow + 8.f)) {
            float tm = fmaxf(lm, __shfl_xor(lm, 16, 64));
            tm = fmaxf(tm, __shfl_xor(tm, 32, 64));
            float mnew = fmaxf(mrow, tm);
            float alpha = __builtin_amdgcn_exp2f(mrow - mnew);
            mrow = mnew;
            lrow *= alpha;
#pragma unroll
            for (int nt = 0; nt < 4; ++nt)
#pragma unroll
                for (int r = 0; r < 4; ++r) O[nt][r] *= alpha;
        }
#pragma unroll
        for (int nt = 0; nt < 4; ++nt)
#pragma unroll
            for (int r = 0; r < 4; ++r)
                s[nt][r] = __builtin_amdgcn_exp2f(s[nt][r] - mrow);
        // per-lane partial sum only (cross-lane reduce deferred to epilogue)
        float r0s = (s[0][0] + s[0][1]) + (s[0][2] + s[0][3]);
        float r1s = (s[1][0] + s[1][1]) + (s[1][2] + s[1][3]);
        float r2s = (s[2][0] + s[2][1]) + (s[2][2] + s[2][3]);
        float r3s = (s[3][0] + s[3][1]) + (s[3][2] + s[3][3]);
        lrow += (r0s + r1s) + (r2s + r3s);

        // P -> per-wave LDS, k-consecutive, XOR-swizzled pad-free rows
#pragma unroll
        for (int nt = 0; nt < 4; ++nt) {
            uint2 u;
            u.x = pk2(s[nt][0], s[nt][1]);
            u.y = pk2(s[nt][2], s[nt][3]);
            *(uint2*)(Pb + ((nt * 32 + quad * 8) ^ hsw)) = u;
        }

        // P A/B-frags (same-wave LDS RAW, in-order per wave)
        short8 pf0 = *(const short8*)(Pb + ((quad * 16) ^ hsw));
        short8 pf1 = *(const short8*)(Pb + ((64 + quad * 16) ^ hsw));

        // O^T += V^T-frag x P-frag
        __builtin_amdgcn_s_setprio(1);
#pragma unroll
        for (int nt = 0; nt < 4; ++nt) {
            int r = nt * 16 + lx;
            short8 vf0 = *(const short8*)&Vs[r * 64 + ((quad ^ (r & 7)) << 3)];
            short8 vf1 = *(const short8*)&Vs[r * 64 + (((4 + quad) ^ (r & 7)) << 3)];
            O[nt] = __builtin_amdgcn_mfma_f32_16x16x32_bf16(vf0, pf0, O[nt], 0, 0, 0);
            O[nt] = __builtin_amdgcn_mfma_f32_16x16x32_bf16(vf1, pf1, O[nt], 0, 0, 0);
        }
        __builtin_amdgcn_s_setprio(0);
    }

    // epilogue: finish the deferred l-reduce, then write O rows
    {
        lrow += __shfl_xor(lrow, 16, 64);
        lrow += __shfl_xor(lrow, 32, 64);
        float invl = 1.f / lrow;
        size_t ro = qbase + (size_t)(qt * 64 + w * 16 + lx) * D_MODEL;
#pragma unroll
        for (int nt = 0; nt < 4; ++nt) {
            uint2 u;
            u.x = pk2(O[nt][0] * invl, O[nt][1] * invl);
            u.y = pk2(O[nt][2] * invl, O[nt][3] * invl);
            *(uint2*)&Hc[ro + nt * 16 + quad * 4] = u;
        }
    }
}

__global__ __launch_bounds__(256) void flash_mfma(
    const ushort_t* __restrict__ Qp, const ushort_t* __restrict__ Kp,
    const ushort_t* __restrict__ Vt, ushort_t* __restrict__ Hc)
{
    __shared__ ushort_t Ks0[64 * 64], Ks1[64 * 64];
    __shared__ ushort_t Vs0[64 * 64], Vs1[64 * 64];
    __shared__ __align__(16) ushort_t Ps[4][16 * 64];   // total LDS = 40960B

    // Block swizzle: flat%8 == bh%8 -> all 32 q-tiles of a head land on one
    // XCD; per-CU slot quartet gets qt = {u, 31-u, (u+8)&31, 31-((u+8)&31)}
    // -> 66 k-iters per CU, balanced.
    const int flat = blockIdx.x;          // 0..1023
    const int c  = flat & 7;              // XCD
    const int j  = flat >> 3;             // 0..127 within XCD
    const int cu = j & 31;                // CU slot heuristic
    const int m  = j >> 5;                // 0..3 co-residency slot
    const int bh = c + (m << 3);          // head group: 4 heads per XCD
    const int u  = (cu + ((m >> 1) << 3)) & 31;
    const int qt = (m & 1) ? (NQT - 1 - u) : u;
    const int b = bh >> 4, h = bh & 15;

    const size_t qbase = (size_t)(b * SEQ) * D_MODEL + h * DK;
    const size_t vbase = (size_t)bh * DK * SEQ;

    flash_tile(qt, qbase, vbase, Qp, Kp, Vt, Hc, Ks0, Ks1, Vs0, Vs1, Ps);
}

extern "C" void kernel_launch(void* const* d_in, const int* in_sizes, int n_in,
                              void* d_out, int out_size, void* d_ws, size_t ws_size,
                              hipStream_t stream) {
    const float* inQ = (const float*)d_in[0];
    const float* inK = (const float*)d_in[1];
    const float* inV = (const float*)d_in[2];
    const float* Wq  = (const float*)d_in[3];
    const float* bq  = (const float*)d_in[4];
    const float* Wk  = (const float*)d_in[5];
    const float* bk  = (const float*)d_in[6];
    const float* Wv  = (const float*)d_in[7];
    const float* bv  = (const float*)d_in[8];
    const float* Wo  = (const float*)d_in[9];
    const float* bo  = (const float*)d_in[10];
    float* out = (float*)d_out;

    const size_t NI = (size_t)MROWS * D_MODEL;      // 4M
    const size_t NW = (size_t)D_MODEL * D_MODEL;    // 1M
    ushort_t* ws  = (ushort_t*)d_ws;
    ushort_t* Qb  = ws;                // bf16 inputs
    ushort_t* Kb  = Qb  + NI;
    ushort_t* Vb  = Kb  + NI;
    ushort_t* Wqb = Vb  + NI;          // bf16 weights
    ushort_t* Wkb = Wqb + NW;
    ushort_t* Wvb = Wkb + NW;
    ushort_t* Wob = Wvb + NW;
    ushort_t* Qp  = Wob + NW;          // projections
    ushort_t* Kp  = Qp  + NI;
    ushort_t* Vtg = Kp  + NI;          // V^T [B*H][DK][SEQ]
    ushort_t* Hc  = Vtg + NI;

    // fp32 -> bf16 (all 7 tensors, one launch)
    cvt_bf16<<<dim3(NI / 1024, 7), 256, 0, stream>>>(
        inQ, inK, inV, Wq, Wk, Wv, Wo,
        Qb, Kb, Vb, Wqb, Wkb, Wvb, Wob, (int)NI, (int)NW);

    // fused QKV projection; Q pre-scaled by 1/sqrt(dk)*log2(e).
    // V^T via transposed gemm: A'=Wvb (rows=channels), W'=Vb (rows=tokens).
    const float qsc = 0.125f * 1.44269504088896340736f;
    GemmArgs aq{Qb, Wqb, bq, (void*)Qp, 0, qsc};
    GemmArgs ak{Kb, Wkb, bk, (void*)Kp, 0, 1.0f};
    GemmArgs av{Wvb, Vb, bv, (void*)Vtg, 1, 1.0f};
    gemm_mfma<<<dim3(MROWS / 128, D_MODEL / 128, 3), 256, 0, stream>>>(aq, ak, av);

    // attention (r9 structure: 1024 blocks, 4/CU, XCD-grouped)
    flash_mfma<<<dim3(NQT * BATCH * NHEADS), 256, 0, stream>>>(Qp, Kp, Vtg, Hc);

    // output projection (fp32 out), 64x128 single-buffer tiles, 512 blocks
    gemm_o<<<dim3(MROWS / 64, D_MODEL / 128), 256, 0, stream>>>(Hc, Wob, bo, out);
}